// Round 3
// baseline (562.416 us; speedup 1.0000x reference)
//
#include <hip/hip_runtime.h>

#define D_MODEL 2048
#define N_HEADS 32
#define D_HEAD  64
#define CHUNK   128
#define SEQ     2048
#define BZ      4
#define NC      16            // SEQ/CHUNK
#define NTOK    (BZ*SEQ)      // 8192
#define LN_EPS  1e-5f

typedef __bf16 bf16_t;
typedef bf16_t bf16x8 __attribute__((ext_vector_type(8)));
typedef float  f32x4  __attribute__((ext_vector_type(4)));

#define GLOBAL_AS __attribute__((address_space(1)))
#define LDS_AS    __attribute__((address_space(3)))

// ---------------------------------------------------------------------------
// K1: LayerNorm + token-shift time-mix -> rx,kx,vx (bf16). Also writes
// xn[:, -1, :] (output 1).
// ---------------------------------------------------------------------------
__global__ __launch_bounds__(256) void k_ln_mix(
    const float* __restrict__ x, const float* __restrict__ tmr,
    const float* __restrict__ tmk, const float* __restrict__ tmv,
    const float* __restrict__ g1, const float* __restrict__ b1,
    bf16_t* __restrict__ rxb, bf16_t* __restrict__ kxb, bf16_t* __restrict__ vxb,
    float* __restrict__ xn_last)
{
    __shared__ float sbuf[16];
    const int row = blockIdx.x;
    const int t = row & (SEQ-1);
    const int tid = threadIdx.x;
    const float4* xc4 = (const float4*)(x + (size_t)row*D_MODEL);
    float4 c0 = xc4[tid*2], c1 = xc4[tid*2+1];
    float4 p0 = {0,0,0,0}, p1 = {0,0,0,0};
    const bool hasprev = (t != 0);
    if (hasprev){
        const float4* xp4 = (const float4*)(x + (size_t)(row-1)*D_MODEL);
        p0 = xp4[tid*2]; p1 = xp4[tid*2+1];
    }
    float xc[8] = {c0.x,c0.y,c0.z,c0.w,c1.x,c1.y,c1.z,c1.w};
    float xp[8] = {p0.x,p0.y,p0.z,p0.w,p1.x,p1.y,p1.z,p1.w};
    float sc=0.f, qc=0.f, sp=0.f, qp=0.f;
    for (int q=0;q<8;++q){ sc+=xc[q]; qc+=xc[q]*xc[q]; sp+=xp[q]; qp+=xp[q]*xp[q]; }
    for (int o=1;o<64;o<<=1){
        sc += __shfl_xor(sc,o,64); qc += __shfl_xor(qc,o,64);
        sp += __shfl_xor(sp,o,64); qp += __shfl_xor(qp,o,64);
    }
    const int wave = tid>>6, lane = tid&63;
    if (lane==0){ sbuf[wave*4+0]=sc; sbuf[wave*4+1]=qc; sbuf[wave*4+2]=sp; sbuf[wave*4+3]=qp; }
    __syncthreads();
    sc = sbuf[0]+sbuf[4]+sbuf[8]+sbuf[12];
    qc = sbuf[1]+sbuf[5]+sbuf[9]+sbuf[13];
    sp = sbuf[2]+sbuf[6]+sbuf[10]+sbuf[14];
    qp = sbuf[3]+sbuf[7]+sbuf[11]+sbuf[15];
    const float inv = 1.f/(float)D_MODEL;
    float muc = sc*inv, varc = qc*inv - muc*muc;
    float rc  = rsqrtf(varc + LN_EPS);
    float mup = sp*inv, varp = qp*inv - mup*mup;
    float rp  = rsqrtf(varp + LN_EPS);
    bf16x8 rv, kv, vv;
    const int ci = tid*8;
    float xnl[8];
    for (int q=0;q<8;++q){
        int c = ci+q;
        float gg = g1[c], bb = b1[c];
        float xn = (xc[q]-muc)*rc*gg + bb;
        float sh = hasprev ? ((xp[q]-mup)*rp*gg + bb) : 0.f;
        float mr = tmr[c], mk = tmk[c], mv = tmv[c];
        rv[q] = (bf16_t)(xn*mr + (1.f-mr)*sh);
        kv[q] = (bf16_t)(xn*mk + (1.f-mk)*sh);
        vv[q] = (bf16_t)(xn*mv + (1.f-mv)*sh);
        xnl[q] = xn;
    }
    size_t base = (size_t)row*D_MODEL + ci;
    *(bf16x8*)&rxb[base] = rv;
    *(bf16x8*)&kxb[base] = kv;
    *(bf16x8*)&vxb[base] = vv;
    if (t == SEQ-1){
        int b = row >> 11;
        for (int q=0;q<8;++q) xn_last[(size_t)b*D_MODEL + ci + q] = xnl[q];
    }
}

// ---------------------------------------------------------------------------
// K2: batched transpose + f32->bf16: WT[z][n][k] = W_z[k][n].
// ---------------------------------------------------------------------------
__global__ __launch_bounds__(256) void k_wt4(
    const float* __restrict__ W0, const float* __restrict__ W1,
    const float* __restrict__ W2, const float* __restrict__ W3,
    bf16_t* __restrict__ WTbase)
{
    __shared__ float tile[64][65];
    const int z = blockIdx.z;
    const float* W = (z==0)?W0:(z==1)?W1:(z==2)?W2:W3;
    bf16_t* WT = WTbase + (size_t)z*D_MODEL*D_MODEL;
    const int n0 = blockIdx.x*64, k0 = blockIdx.y*64;
    const int j = threadIdx.x & 63, i0 = threadIdx.x >> 6;
    for (int it=0; it<16; ++it){
        int i = i0 + it*4;
        tile[j][i] = W[(size_t)(k0+i)*D_MODEL + n0 + j];
    }
    __syncthreads();
    for (int it=0; it<16; ++it){
        int idx = threadIdx.x + it*256;
        int r = idx >> 6, c = idx & 63;
        WT[(size_t)(n0+r)*D_MODEL + k0 + c] = (bf16_t)tile[r][c];
    }
}

// ---------------------------------------------------------------------------
// XCD-aware swizzle for an (8, 32) tile grid.
// ---------------------------------------------------------------------------
__device__ __forceinline__ void xcd_swizzle_8x32(int& bx, int& by)
{
    int id = blockIdx.y*8 + blockIdx.x;      // [0,256)
    int p  = id & 7;
    int n  = id >> 3;                        // per-XCD sequence index [0,32)
    bx = n & 7;
    by = (p<<2) | (n>>3);
}

// ---------------------------------------------------------------------------
// 256x256 8-phase bf16 GEMM core. Frag reads prefetched one phase ahead
// (aP/aQ/bP/bQ) AND interleaved with the MFMA cluster via
// sched_group_barrier (T19): each phase region (between raw barriers) holds
// 16 MFMA + 4/8 ds_read_b128 with no data dependence, so the LDS pipe
// drains UNDER the matrix pipe instead of after it. Without this, the
// per-phase time is MFMA(621cy) + LDS burst(578cy) serialized = measured
// 1206 cy/phase (MfmaUtil 47.8%).
//   vmcnt ledger unchanged (verified): waits only at ph1/ph3, depth 6.
// ---------------------------------------------------------------------------
__device__ __forceinline__ bf16x8 ldfrag(const char* regn, int ks, int row, int quad)
{
    return *(const bf16x8*)(regn + ks*16384 + row*64 + (((quad ^ (row>>1)) & 3) << 4));
}

#define GLD(gp, lp) __builtin_amdgcn_global_load_lds((const GLOBAL_AS void*)(gp), (LDS_AS void*)(lp), 16, 0, 0)
#define STAGE2(gp, lb) do{ GLD((gp), (lb)+tid16); GLD((gp)+rowskip, (lb)+8192+tid16); }while(0)
#define BARX() do{ asm volatile("" ::: "memory"); __builtin_amdgcn_s_barrier(); asm volatile("" ::: "memory"); }while(0)
#define WAITV(n) asm volatile("s_waitcnt vmcnt(" #n ")" ::: "memory")
#define PFA(dst, buf, ks) do{ _Pragma("unroll") \
    for (int mf=0;mf<4;++mf) dst[mf] = ldfrag((buf), (ks), wrow+mf*16+l15, quad); }while(0)
#define PFB(dst, buf, ks, off) do{ _Pragma("unroll") \
    for (int nf=0;nf<4;++nf) dst[nf] = ldfrag((buf), (ks), wcol+(off)+nf*16+l15, quad); }while(0)
#define MMX(AV, BV, CH) do{ \
    _Pragma("unroll") for (int mf=0;mf<4;++mf){ \
    _Pragma("unroll") for (int nf=0;nf<4;++nf)  \
        acc[mf][(CH)*4+nf] = __builtin_amdgcn_mfma_f32_16x16x32_bf16( \
            AV[mf], BV[nf], acc[mf][(CH)*4+nf], 0,0,0); } }while(0)
#define SGB(m,n) __builtin_amdgcn_sched_group_barrier((m),(n),0)
// 16 MFMA + 4 DS_READ region: {MFMA 4, DS 1} x4
#define SGB_PH4() do{ _Pragma("unroll") for (int s_=0;s_<4;++s_){ SGB(0x008,4); SGB(0x100,1);} }while(0)
// 16 MFMA + 8 DS_READ region: {MFMA 2, DS 1} x8
#define SGB_PH8() do{ _Pragma("unroll") for (int s_=0;s_<8;++s_){ SGB(0x008,2); SGB(0x100,1);} }while(0)

template<int OUT_BF16>
__device__ __forceinline__ void gemm256_core(
    const bf16_t* __restrict__ A, const bf16_t* __restrict__ B,
    void* __restrict__ Cout, const float* __restrict__ resid,
    const int N, const int K, char* smem, int bx, int by)
{
    const int tid = threadIdx.x;
    const int lane = tid&63, quad = lane>>4, l15 = lane&15;
    const int wave = tid>>6;
    const int wm = wave>>1, wn = wave&1;         // 4x2 wave grid
    const int wrow = wm*64, wcol = wn*128;       // per-wave C = 64x128
    const int arow0 = by*256, bcol0 = bx*256;
    const int NT = K>>6;
    const int K2 = K*2;
    const int tid16 = tid*16;

    const int rr  = tid>>2;
    const int kcb = (((tid&3) ^ ((tid>>3)&3)) << 4);
    const char* Ag = (const char*)A + (size_t)(arow0 + rr)*K2 + kcb;
    const char* Bg = (const char*)B + (size_t)(bcol0 + rr)*K2 + kcb;
    const int rowskip = 128*K2;

    char* A0 = smem;             char* B0 = smem + 32768;
    char* A1 = smem + 65536;     char* B1 = smem + 98304;

    // prologue: Ak0(0) Bk0(0) Ak1(0) Bk1(0) Ak0(1)  (10 loads)
    STAGE2(Ag,       A0);
    STAGE2(Bg,       B0);
    STAGE2(Ag + 64,  A0 + 16384);
    STAGE2(Bg + 64,  B0 + 16384);
    STAGE2(Ag + 128, A1);
    WAITV(6);                                  // Ak0(0), Bk0(0) retired
    BARX();

    f32x4 acc[4][8];
    #pragma unroll
    for (int i=0;i<4;++i)
        #pragma unroll
        for (int j=0;j<8;++j) acc[i][j] = (f32x4){0.f,0.f,0.f,0.f};

    bf16x8 aP[4], aQ[4], bP[4], bQ[4];
    PFA(aP, A0, 0);            // a ks0, tile 0
    PFB(bP, B0, 0, 0);         // b ks0 ch0, tile 0

    #pragma unroll 2
    for (int t=0; t<NT; ++t){
        const char* As = (t&1) ? A1 : A0;
        const char* Bs = (t&1) ? B1 : B0;
        char* An = (t&1) ? A0 : A1;
        char* Bn = (t&1) ? B0 : B1;
        char* Ac = (t&1) ? A1 : A0;
        const int tn  = (t+1 < NT) ? t+1 : NT-1;
        const int tn2 = (t+2 < NT) ? t+2 : NT-1;
        const char* gA1 = Ag + tn*128;
        const char* gB1 = Bg + tn*128;
        const char* gA2 = Ag + tn2*128;

        // ---- phase 0: MFMA (ks0, ch0) with aP,bP; prefetch bQ = ks0 ch1
        STAGE2(gB1, Bn);                       // Bk0(t+1)
        BARX();
        __builtin_amdgcn_s_setprio(1);
        MMX(aP, bP, 0);
        PFB(bQ, Bs, 0, 64);
        __builtin_amdgcn_s_setprio(0);
        SGB_PH4();
        BARX();
        // ---- phase 1: MFMA (ks0, ch1); prefetch aQ = ks1 A, bP = ks1 ch0
        STAGE2(gA1 + 64, An + 16384);          // Ak1(t+1)
        WAITV(6);
        BARX();
        __builtin_amdgcn_s_setprio(1);
        MMX(aP, bQ, 1);
        PFA(aQ, As, 1);
        PFB(bP, Bs, 1, 0);
        __builtin_amdgcn_s_setprio(0);
        SGB_PH8();
        BARX();
        // ---- phase 2: MFMA (ks1, ch0); prefetch bQ = ks1 ch1
        STAGE2(gB1 + 64, Bn + 16384);          // Bk1(t+1)
        BARX();
        __builtin_amdgcn_s_setprio(1);
        MMX(aQ, bP, 0);
        PFB(bQ, Bs, 1, 64);
        __builtin_amdgcn_s_setprio(0);
        SGB_PH4();
        BARX();
        // ---- phase 3: MFMA (ks1, ch1); prefetch next tile's aP, bP
        STAGE2(gA2, Ac);                       // Ak0(t+2) -> current buf (dead)
        WAITV(6);                              // retires Ak0(t+1), Bk0(t+1)
        BARX();
        __builtin_amdgcn_s_setprio(1);
        MMX(aQ, bQ, 1);
        PFA(aP, An, 0);
        PFB(bP, Bn, 0, 0);
        __builtin_amdgcn_s_setprio(0);
        SGB_PH8();
        BARX();
    }
    WAITV(0);
    __syncthreads();

    if (OUT_BF16){
        bf16_t* Cb = (bf16_t*)Cout;
        bf16_t* Rp = (bf16_t*)smem;            // [256][136]
        #pragma unroll
        for (int jh=0; jh<2; ++jh){
            if (wn == jh){
                #pragma unroll
                for (int mf=0;mf<4;++mf)
                    #pragma unroll
                    for (int nf=0;nf<8;++nf)
                        #pragma unroll
                        for (int e=0;e<4;++e){
                            int rrow = wrow + mf*16 + quad*4 + e;
                            Rp[rrow*136 + nf*16 + l15] = (bf16_t)acc[mf][nf][e];
                        }
            }
            __syncthreads();
            for (int it=0; it<8; ++it){
                int idx = tid + it*512;
                int row = idx >> 4, c8 = (idx & 15)*8;
                *(bf16x8*)&Cb[(size_t)(arow0+row)*N + bcol0 + jh*128 + c8] =
                    *(const bf16x8*)&Rp[row*136 + c8];
            }
            __syncthreads();
        }
    } else {
        float* C = (float*)Cout;
        #pragma unroll
        for (int mf=0;mf<4;++mf)
            #pragma unroll
            for (int nf=0;nf<8;++nf)
                #pragma unroll
                for (int e=0;e<4;++e){
                    size_t r = (size_t)(arow0 + wrow + mf*16 + quad*4 + e);
                    size_t c = (size_t)(bcol0 + wcol + nf*16 + l15);
                    C[r*N + c] = resid[r*N + c] + acc[mf][nf][e];
                }
    }
}

// batched r/k/v GEMM: z selects A/B/C by fixed stride
__global__ __launch_bounds__(512, 2) void k_gemm_rkv(
    const bf16_t* __restrict__ Abase, const bf16_t* __restrict__ Bbase,
    bf16_t* __restrict__ Cbase)
{
    __shared__ __align__(16) char smem[131072];
    const int z = blockIdx.z;
    const bf16_t* A = Abase + (size_t)z*NTOK*D_MODEL;
    const bf16_t* B = Bbase + (size_t)z*D_MODEL*D_MODEL;
    bf16_t*       C = Cbase + (size_t)z*NTOK*D_MODEL;
    int bx, by; xcd_swizzle_8x32(bx, by);
    gemm256_core<1>(A, B, (void*)C, nullptr, D_MODEL, D_MODEL, smem, bx, by);
}

__global__ __launch_bounds__(512, 2) void k_gemm_out(
    const bf16_t* __restrict__ A, const bf16_t* __restrict__ B,
    float* __restrict__ C, const float* __restrict__ resid)
{
    __shared__ __align__(16) char smem[131072];
    int bx, by; xcd_swizzle_8x32(bx, by);
    gemm256_core<0>(A, B, (void*)C, resid, D_MODEL, D_MODEL, smem, bx, by);
}

// ---------------------------------------------------------------------------
// K4b: per (b,chunk,h): U[e][d] = sum_j k[j][e] * w^(C-1-j) * v[j][d]
// ---------------------------------------------------------------------------
__global__ __launch_bounds__(256) void k_chunk_U(
    const bf16_t* __restrict__ kb, const bf16_t* __restrict__ vb,
    const float* __restrict__ td, float* __restrict__ U)
{
    __shared__ __align__(16) bf16_t kT[64*136];
    __shared__ __align__(16) bf16_t vT[64*136];
    const int bid = blockIdx.x;
    const int h = bid & 31, n = (bid>>5)&15, b = bid>>9;
    const int tid = threadIdx.x;
    const int wave = tid>>6, lane = tid&63, quad = lane>>4, l15 = lane&15;
    const size_t row0 = (size_t)b*SEQ + n*CHUNK;
    const int col0 = h*D_HEAD;
    const float lnw = -__expf(td[h]);
    for (int it=0; it<4; ++it){
        int idx = tid + it*256;
        int row = idx>>3, c8 = (idx&7)*8;
        float wj = __expf(lnw * (float)(CHUNK-1-row));
        bf16x8 kv = *(const bf16x8*)&kb[(row0+row)*D_MODEL + col0 + c8];
        bf16x8 vv = *(const bf16x8*)&vb[(row0+row)*D_MODEL + col0 + c8];
        for (int q=0;q<8;++q){
            kT[(c8+q)*136 + row] = (bf16_t)((float)kv[q] * wj);
            vT[(c8+q)*136 + row] = vv[q];
        }
    }
    __syncthreads();
    f32x4 accU[4];
    for (int j=0;j<4;++j) accU[j] = (f32x4){0.f,0.f,0.f,0.f};
    for (int kk=0; kk<4; ++kk){
        bf16x8 af = *(const bf16x8*)&kT[(wave*16+l15)*136 + kk*32 + quad*8];
        bf16x8 bfr[4];
        for (int j=0;j<4;++j) bfr[j] = *(const bf16x8*)&vT[(j*16+l15)*136 + kk*32 + quad*8];
        for (int j=0;j<4;++j)
            accU[j] = __builtin_amdgcn_mfma_f32_16x16x32_bf16(af, bfr[j], accU[j], 0,0,0);
    }
    float* Ub = U + (size_t)bid*(D_HEAD*D_HEAD);
    for (int j=0;j<4;++j) for (int e=0;e<4;++e){
        int ei = wave*16 + quad*4 + e;
        int d  = j*16 + l15;
        Ub[ei*D_HEAD + d] = accU[j][e];
    }
}

// ---------------------------------------------------------------------------
// K5: sequential prefix over chunks. Per-element independent scan ->
// 256 blocks x 256 threads x 8 elements, fully coalesced (bf16x8 / float4).
// stT stored in U layout [e][d]; k_att_fused transposes when staging.
// ---------------------------------------------------------------------------
__global__ __launch_bounds__(256) void k_scan(
    const float* __restrict__ U, const float* __restrict__ td,
    bf16_t* __restrict__ stT, float* __restrict__ outState)
{
    const int blk = blockIdx.x;          // 256 = 128 bh x 2 slices
    const int bh = blk >> 1, sl = blk & 1;
    const int h = bh & 31, b = bh >> 5;
    const int f8 = (sl*256 + threadIdx.x)*8;   // [0,4096)
    const float lnw = -__expf(td[h]);
    const float wC  =  __expf(lnw * (float)CHUNK);
    float st[8];
    #pragma unroll
    for (int q=0;q<8;++q) st[q] = 0.f;
    for (int n=0;n<NC;++n){
        size_t base = ((size_t)((b*NC + n)*N_HEADS + h))*4096;
        bf16x8 s8;
        #pragma unroll
        for (int q=0;q<8;++q) s8[q] = (bf16_t)st[q];
        *(bf16x8*)&stT[base + f8] = s8;
        float4 u0 = *(const float4*)&U[base + f8];
        float4 u1 = *(const float4*)&U[base + f8 + 4];
        float uu[8] = {u0.x,u0.y,u0.z,u0.w,u1.x,u1.y,u1.z,u1.w};
        #pragma unroll
        for (int q=0;q<8;++q) st[q] = st[q]*wC + uu[q];
    }
    size_t ob = ((size_t)(b*N_HEADS + h))*4096 + f8;
    #pragma unroll
    for (int q=0;q<8;++q) outState[ob + q] = st[q];
}

// ---------------------------------------------------------------------------
// K6: fused per (b,chunk,h): S=(r k^T)*mask -> P=S v -> bias=(r state)*w^i ->
// LN over d_head -> att bf16. Decay powers from a 128-entry LDS table.
// ---------------------------------------------------------------------------
__global__ __launch_bounds__(256) void k_att_fused(
    const bf16_t* __restrict__ rb, const bf16_t* __restrict__ kb, const bf16_t* __restrict__ vb,
    const bf16_t* __restrict__ stT, const float* __restrict__ td, const float* __restrict__ tf,
    const float* __restrict__ gx, const float* __restrict__ bx,
    bf16_t* __restrict__ att)
{
    __shared__ __align__(16) char smem[64000];
    bf16_t* rS  = (bf16_t*)smem;               // [128][72]
    bf16_t* kS  = (bf16_t*)(smem + 18432);     // [128][72]; later Sst [128][40], att_s [128][72]
    bf16_t* vT  = (bf16_t*)(smem + 36864);     // [64][136]
    bf16_t* sS  = (bf16_t*)(smem + 54272);     // [64][72]
    float*  wpS = (float*)(smem + 63488);      // [128] decay powers
    bf16_t* Sst = kS;
    bf16_t* att_s = kS;
    const int bid = blockIdx.x;
    const int h = bid & 31, n = (bid>>5)&15, b = bid>>9;
    const int tid = threadIdx.x;
    const int wave = tid>>6, lane = tid&63, quad = lane>>4, l15 = lane&15;
    const size_t row0 = (size_t)b*SEQ + n*CHUNK;
    const int col0 = h*D_HEAD;
    const float lnw = -__expf(td[h]);
    const float u   =  __expf(tf[h]);
    if (tid < 128) wpS[tid] = __expf(lnw * (float)tid);
    for (int it=0; it<4; ++it){
        int idx = tid + it*256;
        int row = idx>>3, c8 = (idx&7)*8;
        *(bf16x8*)&rS[row*72 + c8] = *(const bf16x8*)&rb[(row0+row)*D_MODEL + col0 + c8];
        *(bf16x8*)&kS[row*72 + c8] = *(const bf16x8*)&kb[(row0+row)*D_MODEL + col0 + c8];
        bf16x8 vv = *(const bf16x8*)&vb[(row0+row)*D_MODEL + col0 + c8];
        for (int q=0;q<8;++q) vT[(c8+q)*136 + row] = vv[q];
    }
    // state staged transposed: sS[d][e] = stg[e][d]
    const bf16_t* stg = stT + (size_t)bid*4096;
    for (int it=0; it<2; ++it){
        int idx = tid + it*256;
        int row = idx>>3, c8 = (idx&7)*8;       // row = e, c8.. = d
        bf16x8 sv = *(const bf16x8*)&stg[row*64 + c8];
        for (int q=0;q<8;++q) sS[(c8+q)*72 + row] = sv[q];
    }
    __syncthreads();
    // --- S = r k^T (full 128x128 in registers)
    f32x4 accS[2][8];
    for (int i=0;i<2;++i) for (int j=0;j<8;++j) accS[i][j] = (f32x4){0.f,0.f,0.f,0.f};
    for (int kk=0; kk<2; ++kk){
        bf16x8 af[2], bfr[8];
        for (int i=0;i<2;++i) af[i] = *(const bf16x8*)&rS[(wave*32+i*16+l15)*72 + kk*32 + quad*8];
        for (int j=0;j<8;++j) bfr[j] = *(const bf16x8*)&kS[(j*16+l15)*72 + kk*32 + quad*8];
        for (int i=0;i<2;++i) for (int j=0;j<8;++j)
            accS[i][j] = __builtin_amdgcn_mfma_f32_16x16x32_bf16(af[i], bfr[j], accS[i][j], 0,0,0);
    }
    __syncthreads();   // kS dead; Sst overlays it
    // --- P = (S*mask) v, staged 32 columns at a time
    f32x4 accP[2][4];
    for (int i=0;i<2;++i) for (int j=0;j<4;++j) accP[i][j] = (f32x4){0.f,0.f,0.f,0.f};
    for (int kk=0; kk<4; ++kk){
        for (int i=0;i<2;++i) for (int jj=0;jj<2;++jj) for (int e=0;e<4;++e){
            int si = wave*32 + i*16 + quad*4 + e;
            int sj = kk*32 + jj*16 + l15;
            float m;
            if (si > sj)       m = wpS[si-sj-1];
            else if (si == sj) m = u;
            else               m = 0.f;
            Sst[si*40 + jj*16 + l15] = (bf16_t)(accS[i][kk*2+jj][e] * m);
        }
        __syncthreads();
        bf16x8 af[2], bfr[4];
        for (int i=0;i<2;++i) af[i] = *(const bf16x8*)&Sst[(wave*32+i*16+l15)*40 + quad*8];
        for (int j=0;j<4;++j) bfr[j] = *(const bf16x8*)&vT[(j*16+l15)*136 + kk*32 + quad*8];
        for (int i=0;i<2;++i) for (int j=0;j<4;++j)
            accP[i][j] = __builtin_amdgcn_mfma_f32_16x16x32_bf16(af[i], bfr[j], accP[i][j], 0,0,0);
        __syncthreads();
    }
    // --- bias = r @ state (state staged transposed: sS[d][e])
    f32x4 accB[2][4];
    for (int i=0;i<2;++i) for (int j=0;j<4;++j) accB[i][j] = (f32x4){0.f,0.f,0.f,0.f};
    for (int kk=0; kk<2; ++kk){
        bf16x8 af[2], bfr[4];
        for (int i=0;i<2;++i) af[i] = *(const bf16x8*)&rS[(wave*32+i*16+l15)*72 + kk*32 + quad*8];
        for (int j=0;j<4;++j) bfr[j] = *(const bf16x8*)&sS[(j*16+l15)*72 + kk*32 + quad*8];
        for (int i=0;i<2;++i) for (int j=0;j<4;++j)
            accB[i][j] = __builtin_amdgcn_mfma_f32_16x16x32_bf16(af[i], bfr[j], accB[i][j], 0,0,0);
    }
    // --- combine + in-register LayerNorm over d
    float pre[2][4][4];
    float mu_r[2][4], rs_r[2][4];
    for (int i=0;i<2;++i) for (int e=0;e<4;++e){
        int si = wave*32 + i*16 + quad*4 + e;
        float wsi = wpS[si];
        float s = 0.f, q2 = 0.f;
        for (int j=0;j<4;++j){
            float v = accP[i][j][e] + accB[i][j][e]*wsi;
            pre[i][j][e] = v;
            s += v; q2 += v*v;
        }
        for (int o=1;o<16;o<<=1){ s += __shfl_xor(s,o,64); q2 += __shfl_xor(q2,o,64); }
        float mu = s*(1.f/64.f);
        float var = q2*(1.f/64.f) - mu*mu;
        mu_r[i][e] = mu; rs_r[i][e] = rsqrtf(var + LN_EPS);
    }
    float gxv[4], bxv[4];
    for (int j=0;j<4;++j){ gxv[j] = gx[col0 + j*16 + l15]; bxv[j] = bx[col0 + j*16 + l15]; }
    for (int i=0;i<2;++i) for (int j=0;j<4;++j) for (int e=0;e<4;++e){
        int si = wave*32 + i*16 + quad*4 + e;
        att_s[si*72 + j*16 + l15] = (bf16_t)((pre[i][j][e]-mu_r[i][e])*rs_r[i][e]*gxv[j] + bxv[j]);
    }
    __syncthreads();
    for (int it=0; it<4; ++it){
        int idx = tid + it*256;
        int row = idx>>3, c8 = (idx&7)*8;
        *(bf16x8*)&att[(row0+row)*D_MODEL + col0 + c8] = *(const bf16x8*)&att_s[row*72 + c8];
    }
}

// ---------------------------------------------------------------------------
// Launch. Workspace (>= 224 MiB), aliasing:
//   [0,32)    rxb bf16   -> U f32 (after rkv GEMM)
//   [32,64)   kxb bf16   -> stT bf16
//   [64,96)   vxb bf16   -> att bf16
//   [96,128)  WT[4] bf16 (Wr,Wk,Wv,Wo transposed; Wo alive to end)
//   [128,160) rb, [160,192) kb, [192,224) vb
// ---------------------------------------------------------------------------
extern "C" void kernel_launch(void* const* d_in, const int* in_sizes, int n_in,
                              void* d_out, int out_size, void* d_ws, size_t ws_size,
                              hipStream_t stream) {
    const float* x   = (const float*)d_in[0];
    const float* tmr = (const float*)d_in[1];
    const float* tmk = (const float*)d_in[2];
    const float* tmv = (const float*)d_in[3];
    const float* Wk  = (const float*)d_in[4];
    const float* Wv  = (const float*)d_in[5];
    const float* Wr  = (const float*)d_in[6];
    const float* Wo  = (const float*)d_in[7];
    const float* td  = (const float*)d_in[8];
    const float* tf  = (const float*)d_in[9];
    const float* g1  = (const float*)d_in[10];
    const float* b1  = (const float*)d_in[11];
    const float* gx  = (const float*)d_in[12];
    const float* bx  = (const float*)d_in[13];

    float* out0 = (float*)d_out;
    float* out1 = out0 + (size_t)NTOK*D_MODEL;
    float* out2 = out1 + (size_t)BZ*D_MODEL;

    const size_t MB = 1ull<<20;
    char* ws = (char*)d_ws;
    bf16_t* rxb = (bf16_t*)(ws);
    bf16_t* kxb = (bf16_t*)(ws + 32*MB);
    bf16_t* vxb = (bf16_t*)(ws + 64*MB);
    bf16_t* WTb = (bf16_t*)(ws + 96*MB);          // 4 x 8MB: Wr,Wk,Wv,Wo
    bf16_t* WoT = (bf16_t*)(ws + 120*MB);
    bf16_t* rb  = (bf16_t*)(ws + 128*MB);
    float*  U   = (float*)(ws);                   // after rxb dead
    bf16_t* stT = (bf16_t*)(ws + 32*MB);          // after kxb dead
    bf16_t* att = (bf16_t*)(ws + 64*MB);          // after vxb dead
    bf16_t* kb  = (bf16_t*)(ws + 160*MB);
    bf16_t* vb  = (bf16_t*)(ws + 192*MB);

    k_ln_mix<<<NTOK, 256, 0, stream>>>(x, tmr, tmk, tmv, g1, b1, rxb, kxb, vxb, out1);

    dim3 gT(32, 32, 4);
    k_wt4<<<gT, 256, 0, stream>>>(Wr, Wk, Wv, Wo, WTb);

    dim3 gG3(D_MODEL/256, NTOK/256, 3);   // (8, 32, 3)
    k_gemm_rkv<<<gG3, 512, 0, stream>>>(rxb, WTb, rb);

    const int nblk = BZ*NC*N_HEADS;   // 2048
    k_chunk_U <<<nblk, 256, 0, stream>>>(kb, vb, td, U);
    k_scan    <<<256, 256, 0, stream>>>(U, td, stT, out2);
    k_att_fused<<<nblk, 256, 0, stream>>>(rb, kb, vb, stT, td, tf, gx, bx, att);

    dim3 gG(D_MODEL/256, NTOK/256);       // (8, 32)
    k_gemm_out<<<gG, 512, 0, stream>>>(att, WoT, out0, x);
}

// Round 4
// 555.133 us; speedup vs baseline: 1.0131x; 1.0131x over previous
//
#include <hip/hip_runtime.h>

#define D_MODEL 2048
#define N_HEADS 32
#define D_HEAD  64
#define CHUNK   128
#define SEQ     2048
#define BZ      4
#define NC      16            // SEQ/CHUNK
#define NTOK    (BZ*SEQ)      // 8192
#define LN_EPS  1e-5f

typedef __bf16 bf16_t;
typedef bf16_t bf16x8 __attribute__((ext_vector_type(8)));
typedef float  f32x4  __attribute__((ext_vector_type(4)));

#define GLOBAL_AS __attribute__((address_space(1)))
#define LDS_AS    __attribute__((address_space(3)))

// ---------------------------------------------------------------------------
// K1: LayerNorm + token-shift time-mix -> rx,kx,vx (bf16). Also writes
// xn[:, -1, :] (output 1).
// ---------------------------------------------------------------------------
__global__ __launch_bounds__(256) void k_ln_mix(
    const float* __restrict__ x, const float* __restrict__ tmr,
    const float* __restrict__ tmk, const float* __restrict__ tmv,
    const float* __restrict__ g1, const float* __restrict__ b1,
    bf16_t* __restrict__ rxb, bf16_t* __restrict__ kxb, bf16_t* __restrict__ vxb,
    float* __restrict__ xn_last)
{
    __shared__ float sbuf[16];
    const int row = blockIdx.x;
    const int t = row & (SEQ-1);
    const int tid = threadIdx.x;
    const float4* xc4 = (const float4*)(x + (size_t)row*D_MODEL);
    float4 c0 = xc4[tid*2], c1 = xc4[tid*2+1];
    float4 p0 = {0,0,0,0}, p1 = {0,0,0,0};
    const bool hasprev = (t != 0);
    if (hasprev){
        const float4* xp4 = (const float4*)(x + (size_t)(row-1)*D_MODEL);
        p0 = xp4[tid*2]; p1 = xp4[tid*2+1];
    }
    float xc[8] = {c0.x,c0.y,c0.z,c0.w,c1.x,c1.y,c1.z,c1.w};
    float xp[8] = {p0.x,p0.y,p0.z,p0.w,p1.x,p1.y,p1.z,p1.w};
    float sc=0.f, qc=0.f, sp=0.f, qp=0.f;
    for (int q=0;q<8;++q){ sc+=xc[q]; qc+=xc[q]*xc[q]; sp+=xp[q]; qp+=xp[q]*xp[q]; }
    for (int o=1;o<64;o<<=1){
        sc += __shfl_xor(sc,o,64); qc += __shfl_xor(qc,o,64);
        sp += __shfl_xor(sp,o,64); qp += __shfl_xor(qp,o,64);
    }
    const int wave = tid>>6, lane = tid&63;
    if (lane==0){ sbuf[wave*4+0]=sc; sbuf[wave*4+1]=qc; sbuf[wave*4+2]=sp; sbuf[wave*4+3]=qp; }
    __syncthreads();
    sc = sbuf[0]+sbuf[4]+sbuf[8]+sbuf[12];
    qc = sbuf[1]+sbuf[5]+sbuf[9]+sbuf[13];
    sp = sbuf[2]+sbuf[6]+sbuf[10]+sbuf[14];
    qp = sbuf[3]+sbuf[7]+sbuf[11]+sbuf[15];
    const float inv = 1.f/(float)D_MODEL;
    float muc = sc*inv, varc = qc*inv - muc*muc;
    float rc  = rsqrtf(varc + LN_EPS);
    float mup = sp*inv, varp = qp*inv - mup*mup;
    float rp  = rsqrtf(varp + LN_EPS);
    bf16x8 rv, kv, vv;
    const int ci = tid*8;
    float xnl[8];
    for (int q=0;q<8;++q){
        int c = ci+q;
        float gg = g1[c], bb = b1[c];
        float xn = (xc[q]-muc)*rc*gg + bb;
        float sh = hasprev ? ((xp[q]-mup)*rp*gg + bb) : 0.f;
        float mr = tmr[c], mk = tmk[c], mv = tmv[c];
        rv[q] = (bf16_t)(xn*mr + (1.f-mr)*sh);
        kv[q] = (bf16_t)(xn*mk + (1.f-mk)*sh);
        vv[q] = (bf16_t)(xn*mv + (1.f-mv)*sh);
        xnl[q] = xn;
    }
    size_t base = (size_t)row*D_MODEL + ci;
    *(bf16x8*)&rxb[base] = rv;
    *(bf16x8*)&kxb[base] = kv;
    *(bf16x8*)&vxb[base] = vv;
    if (t == SEQ-1){
        int b = row >> 11;
        for (int q=0;q<8;++q) xn_last[(size_t)b*D_MODEL + ci + q] = xnl[q];
    }
}

// ---------------------------------------------------------------------------
// K2: batched transpose + f32->bf16: WT[z][n][k] = W_z[k][n].
// ---------------------------------------------------------------------------
__global__ __launch_bounds__(256) void k_wt4(
    const float* __restrict__ W0, const float* __restrict__ W1,
    const float* __restrict__ W2, const float* __restrict__ W3,
    bf16_t* __restrict__ WTbase)
{
    __shared__ float tile[64][65];
    const int z = blockIdx.z;
    const float* W = (z==0)?W0:(z==1)?W1:(z==2)?W2:W3;
    bf16_t* WT = WTbase + (size_t)z*D_MODEL*D_MODEL;
    const int n0 = blockIdx.x*64, k0 = blockIdx.y*64;
    const int j = threadIdx.x & 63, i0 = threadIdx.x >> 6;
    for (int it=0; it<16; ++it){
        int i = i0 + it*4;
        tile[j][i] = W[(size_t)(k0+i)*D_MODEL + n0 + j];
    }
    __syncthreads();
    for (int it=0; it<16; ++it){
        int idx = threadIdx.x + it*256;
        int r = idx >> 6, c = idx & 63;
        WT[(size_t)(n0+r)*D_MODEL + k0 + c] = (bf16_t)tile[r][c];
    }
}

// ---------------------------------------------------------------------------
// XCD-aware swizzle for an (8, 32) tile grid.
// ---------------------------------------------------------------------------
__device__ __forceinline__ void xcd_swizzle_8x32(int& bx, int& by)
{
    int id = blockIdx.y*8 + blockIdx.x;      // [0,256)
    int p  = id & 7;
    int n  = id >> 3;                        // per-XCD sequence index [0,32)
    bx = n & 7;
    by = (p<<2) | (n>>3);
}

// ---------------------------------------------------------------------------
// 256x256 8-phase bf16 GEMM core. Frag reads prefetched one phase ahead
// (aP/aQ/bP/bQ). The MFMA cluster and the next-phase ds_reads are data-
// independent; sched_group_barrier directives INSIDE the same scheduling
// region (between setprio(1) and setprio(0) -- both are region boundaries,
// as are the barrier asm blocks) force an alternating MFMA/DS_READ emission
// so the LDS pipe drains under the matrix pipe. (Round-2 attempt placed the
// SGBs after setprio(0) -> empty region -> null. This is the corrected A/B.)
//   vmcnt ledger unchanged (verified): waits only at ph1/ph3, depth 6.
// ---------------------------------------------------------------------------
__device__ __forceinline__ bf16x8 ldfrag(const char* regn, int ks, int row, int quad)
{
    return *(const bf16x8*)(regn + ks*16384 + row*64 + (((quad ^ (row>>1)) & 3) << 4));
}

#define GLD(gp, lp) __builtin_amdgcn_global_load_lds((const GLOBAL_AS void*)(gp), (LDS_AS void*)(lp), 16, 0, 0)
#define STAGE2(gp, lb) do{ GLD((gp), (lb)+tid16); GLD((gp)+rowskip, (lb)+8192+tid16); }while(0)
#define BARX() do{ asm volatile("" ::: "memory"); __builtin_amdgcn_s_barrier(); asm volatile("" ::: "memory"); }while(0)
#define WAITV(n) asm volatile("s_waitcnt vmcnt(" #n ")" ::: "memory")
#define PFA(dst, buf, ks) do{ _Pragma("unroll") \
    for (int mf=0;mf<4;++mf) dst[mf] = ldfrag((buf), (ks), wrow+mf*16+l15, quad); }while(0)
#define PFB(dst, buf, ks, off) do{ _Pragma("unroll") \
    for (int nf=0;nf<4;++nf) dst[nf] = ldfrag((buf), (ks), wcol+(off)+nf*16+l15, quad); }while(0)
#define MMX(AV, BV, CH) do{ \
    _Pragma("unroll") for (int mf=0;mf<4;++mf){ \
    _Pragma("unroll") for (int nf=0;nf<4;++nf)  \
        acc[mf][(CH)*4+nf] = __builtin_amdgcn_mfma_f32_16x16x32_bf16( \
            AV[mf], BV[nf], acc[mf][(CH)*4+nf], 0,0,0); } }while(0)
#define SGB(m,n) __builtin_amdgcn_sched_group_barrier((m),(n),0)
// 16 MFMA + 4 DS_READ region: {MFMA 4, DS 1} x4
#define SGB_PH4() do{ _Pragma("unroll") for (int s_=0;s_<4;++s_){ SGB(0x008,4); SGB(0x100,1);} }while(0)
// 16 MFMA + 8 DS_READ region: {MFMA 2, DS 1} x8
#define SGB_PH8() do{ _Pragma("unroll") for (int s_=0;s_<8;++s_){ SGB(0x008,2); SGB(0x100,1);} }while(0)

template<int OUT_BF16>
__device__ __forceinline__ void gemm256_core(
    const bf16_t* __restrict__ A, const bf16_t* __restrict__ B,
    void* __restrict__ Cout, const float* __restrict__ resid,
    const int N, const int K, char* smem, int bx, int by)
{
    const int tid = threadIdx.x;
    const int lane = tid&63, quad = lane>>4, l15 = lane&15;
    const int wave = tid>>6;
    const int wm = wave>>1, wn = wave&1;         // 4x2 wave grid
    const int wrow = wm*64, wcol = wn*128;       // per-wave C = 64x128
    const int arow0 = by*256, bcol0 = bx*256;
    const int NT = K>>6;
    const int K2 = K*2;
    const int tid16 = tid*16;

    const int rr  = tid>>2;
    const int kcb = (((tid&3) ^ ((tid>>3)&3)) << 4);
    const char* Ag = (const char*)A + (size_t)(arow0 + rr)*K2 + kcb;
    const char* Bg = (const char*)B + (size_t)(bcol0 + rr)*K2 + kcb;
    const int rowskip = 128*K2;

    char* A0 = smem;             char* B0 = smem + 32768;
    char* A1 = smem + 65536;     char* B1 = smem + 98304;

    // prologue: Ak0(0) Bk0(0) Ak1(0) Bk1(0) Ak0(1)  (10 loads)
    STAGE2(Ag,       A0);
    STAGE2(Bg,       B0);
    STAGE2(Ag + 64,  A0 + 16384);
    STAGE2(Bg + 64,  B0 + 16384);
    STAGE2(Ag + 128, A1);
    WAITV(6);                                  // Ak0(0), Bk0(0) retired
    BARX();

    f32x4 acc[4][8];
    #pragma unroll
    for (int i=0;i<4;++i)
        #pragma unroll
        for (int j=0;j<8;++j) acc[i][j] = (f32x4){0.f,0.f,0.f,0.f};

    bf16x8 aP[4], aQ[4], bP[4], bQ[4];
    PFA(aP, A0, 0);            // a ks0, tile 0
    PFB(bP, B0, 0, 0);         // b ks0 ch0, tile 0

    #pragma unroll 2
    for (int t=0; t<NT; ++t){
        const char* As = (t&1) ? A1 : A0;
        const char* Bs = (t&1) ? B1 : B0;
        char* An = (t&1) ? A0 : A1;
        char* Bn = (t&1) ? B0 : B1;
        char* Ac = (t&1) ? A1 : A0;
        const int tn  = (t+1 < NT) ? t+1 : NT-1;
        const int tn2 = (t+2 < NT) ? t+2 : NT-1;
        const char* gA1 = Ag + tn*128;
        const char* gB1 = Bg + tn*128;
        const char* gA2 = Ag + tn2*128;

        // ---- phase 0: MFMA (ks0, ch0) with aP,bP; prefetch bQ = ks0 ch1
        STAGE2(gB1, Bn);                       // Bk0(t+1)
        BARX();
        __builtin_amdgcn_s_setprio(1);
        MMX(aP, bP, 0);
        PFB(bQ, Bs, 0, 64);
        SGB_PH4();
        __builtin_amdgcn_s_setprio(0);
        BARX();
        // ---- phase 1: MFMA (ks0, ch1); prefetch aQ = ks1 A, bP = ks1 ch0
        STAGE2(gA1 + 64, An + 16384);          // Ak1(t+1)
        WAITV(6);
        BARX();
        __builtin_amdgcn_s_setprio(1);
        MMX(aP, bQ, 1);
        PFA(aQ, As, 1);
        PFB(bP, Bs, 1, 0);
        SGB_PH8();
        __builtin_amdgcn_s_setprio(0);
        BARX();
        // ---- phase 2: MFMA (ks1, ch0); prefetch bQ = ks1 ch1
        STAGE2(gB1 + 64, Bn + 16384);          // Bk1(t+1)
        BARX();
        __builtin_amdgcn_s_setprio(1);
        MMX(aQ, bP, 0);
        PFB(bQ, Bs, 1, 64);
        SGB_PH4();
        __builtin_amdgcn_s_setprio(0);
        BARX();
        // ---- phase 3: MFMA (ks1, ch1); prefetch next tile's aP, bP
        STAGE2(gA2, Ac);                       // Ak0(t+2) -> current buf (dead)
        WAITV(6);                              // retires Ak0(t+1), Bk0(t+1)
        BARX();
        __builtin_amdgcn_s_setprio(1);
        MMX(aQ, bQ, 1);
        PFA(aP, An, 0);
        PFB(bP, Bn, 0, 0);
        SGB_PH8();
        __builtin_amdgcn_s_setprio(0);
        BARX();
    }
    WAITV(0);
    __syncthreads();

    if (OUT_BF16){
        bf16_t* Cb = (bf16_t*)Cout;
        bf16_t* Rp = (bf16_t*)smem;            // [256][136]
        #pragma unroll
        for (int jh=0; jh<2; ++jh){
            if (wn == jh){
                #pragma unroll
                for (int mf=0;mf<4;++mf)
                    #pragma unroll
                    for (int nf=0;nf<8;++nf)
                        #pragma unroll
                        for (int e=0;e<4;++e){
                            int rrow = wrow + mf*16 + quad*4 + e;
                            Rp[rrow*136 + nf*16 + l15] = (bf16_t)acc[mf][nf][e];
                        }
            }
            __syncthreads();
            for (int it=0; it<8; ++it){
                int idx = tid + it*512;
                int row = idx >> 4, c8 = (idx & 15)*8;
                *(bf16x8*)&Cb[(size_t)(arow0+row)*N + bcol0 + jh*128 + c8] =
                    *(const bf16x8*)&Rp[row*136 + c8];
            }
            __syncthreads();
        }
    } else {
        float* C = (float*)Cout;
        #pragma unroll
        for (int mf=0;mf<4;++mf)
            #pragma unroll
            for (int nf=0;nf<8;++nf)
                #pragma unroll
                for (int e=0;e<4;++e){
                    size_t r = (size_t)(arow0 + wrow + mf*16 + quad*4 + e);
                    size_t c = (size_t)(bcol0 + wcol + nf*16 + l15);
                    C[r*N + c] = resid[r*N + c] + acc[mf][nf][e];
                }
    }
}

// batched r/k/v GEMM: z selects A/B/C by fixed stride
__global__ __launch_bounds__(512, 2) void k_gemm_rkv(
    const bf16_t* __restrict__ Abase, const bf16_t* __restrict__ Bbase,
    bf16_t* __restrict__ Cbase)
{
    __shared__ __align__(16) char smem[131072];
    const int z = blockIdx.z;
    const bf16_t* A = Abase + (size_t)z*NTOK*D_MODEL;
    const bf16_t* B = Bbase + (size_t)z*D_MODEL*D_MODEL;
    bf16_t*       C = Cbase + (size_t)z*NTOK*D_MODEL;
    int bx, by; xcd_swizzle_8x32(bx, by);
    gemm256_core<1>(A, B, (void*)C, nullptr, D_MODEL, D_MODEL, smem, bx, by);
}

__global__ __launch_bounds__(512, 2) void k_gemm_out(
    const bf16_t* __restrict__ A, const bf16_t* __restrict__ B,
    float* __restrict__ C, const float* __restrict__ resid)
{
    __shared__ __align__(16) char smem[131072];
    int bx, by; xcd_swizzle_8x32(bx, by);
    gemm256_core<0>(A, B, (void*)C, resid, D_MODEL, D_MODEL, smem, bx, by);
}

// ---------------------------------------------------------------------------
// K4b: per (b,chunk,h): U[e][d] = sum_j k[j][e] * w^(C-1-j) * v[j][d]
// ---------------------------------------------------------------------------
__global__ __launch_bounds__(256) void k_chunk_U(
    const bf16_t* __restrict__ kb, const bf16_t* __restrict__ vb,
    const float* __restrict__ td, float* __restrict__ U)
{
    __shared__ __align__(16) bf16_t kT[64*136];
    __shared__ __align__(16) bf16_t vT[64*136];
    const int bid = blockIdx.x;
    const int h = bid & 31, n = (bid>>5)&15, b = bid>>9;
    const int tid = threadIdx.x;
    const int wave = tid>>6, lane = tid&63, quad = lane>>4, l15 = lane&15;
    const size_t row0 = (size_t)b*SEQ + n*CHUNK;
    const int col0 = h*D_HEAD;
    const float lnw = -__expf(td[h]);
    for (int it=0; it<4; ++it){
        int idx = tid + it*256;
        int row = idx>>3, c8 = (idx&7)*8;
        float wj = __expf(lnw * (float)(CHUNK-1-row));
        bf16x8 kv = *(const bf16x8*)&kb[(row0+row)*D_MODEL + col0 + c8];
        bf16x8 vv = *(const bf16x8*)&vb[(row0+row)*D_MODEL + col0 + c8];
        for (int q=0;q<8;++q){
            kT[(c8+q)*136 + row] = (bf16_t)((float)kv[q] * wj);
            vT[(c8+q)*136 + row] = vv[q];
        }
    }
    __syncthreads();
    f32x4 accU[4];
    for (int j=0;j<4;++j) accU[j] = (f32x4){0.f,0.f,0.f,0.f};
    for (int kk=0; kk<4; ++kk){
        bf16x8 af = *(const bf16x8*)&kT[(wave*16+l15)*136 + kk*32 + quad*8];
        bf16x8 bfr[4];
        for (int j=0;j<4;++j) bfr[j] = *(const bf16x8*)&vT[(j*16+l15)*136 + kk*32 + quad*8];
        for (int j=0;j<4;++j)
            accU[j] = __builtin_amdgcn_mfma_f32_16x16x32_bf16(af, bfr[j], accU[j], 0,0,0);
    }
    float* Ub = U + (size_t)bid*(D_HEAD*D_HEAD);
    for (int j=0;j<4;++j) for (int e=0;e<4;++e){
        int ei = wave*16 + quad*4 + e;
        int d  = j*16 + l15;
        Ub[ei*D_HEAD + d] = accU[j][e];
    }
}

// ---------------------------------------------------------------------------
// K5: sequential prefix over chunks. Per-element independent scan ->
// 256 blocks x 256 threads x 8 elements, fully coalesced (bf16x8 / float4).
// stT stored in U layout [e][d]; k_att_fused transposes when staging.
// ---------------------------------------------------------------------------
__global__ __launch_bounds__(256) void k_scan(
    const float* __restrict__ U, const float* __restrict__ td,
    bf16_t* __restrict__ stT, float* __restrict__ outState)
{
    const int blk = blockIdx.x;          // 256 = 128 bh x 2 slices
    const int bh = blk >> 1, sl = blk & 1;
    const int h = bh & 31, b = bh >> 5;
    const int f8 = (sl*256 + threadIdx.x)*8;   // [0,4096)
    const float lnw = -__expf(td[h]);
    const float wC  =  __expf(lnw * (float)CHUNK);
    float st[8];
    #pragma unroll
    for (int q=0;q<8;++q) st[q] = 0.f;
    for (int n=0;n<NC;++n){
        size_t base = ((size_t)((b*NC + n)*N_HEADS + h))*4096;
        bf16x8 s8;
        #pragma unroll
        for (int q=0;q<8;++q) s8[q] = (bf16_t)st[q];
        *(bf16x8*)&stT[base + f8] = s8;
        float4 u0 = *(const float4*)&U[base + f8];
        float4 u1 = *(const float4*)&U[base + f8 + 4];
        float uu[8] = {u0.x,u0.y,u0.z,u0.w,u1.x,u1.y,u1.z,u1.w};
        #pragma unroll
        for (int q=0;q<8;++q) st[q] = st[q]*wC + uu[q];
    }
    size_t ob = ((size_t)(b*N_HEADS + h))*4096 + f8;
    #pragma unroll
    for (int q=0;q<8;++q) outState[ob + q] = st[q];
}

// ---------------------------------------------------------------------------
// K6: fused per (b,chunk,h): S=(r k^T)*mask -> P=S v -> bias=(r state)*w^i ->
// LN over d_head -> att bf16. Decay powers from a 128-entry LDS table.
// ---------------------------------------------------------------------------
__global__ __launch_bounds__(256) void k_att_fused(
    const bf16_t* __restrict__ rb, const bf16_t* __restrict__ kb, const bf16_t* __restrict__ vb,
    const bf16_t* __restrict__ stT, const float* __restrict__ td, const float* __restrict__ tf,
    const float* __restrict__ gx, const float* __restrict__ bx,
    bf16_t* __restrict__ att)
{
    __shared__ __align__(16) char smem[64000];
    bf16_t* rS  = (bf16_t*)smem;               // [128][72]
    bf16_t* kS  = (bf16_t*)(smem + 18432);     // [128][72]; later Sst [128][40], att_s [128][72]
    bf16_t* vT  = (bf16_t*)(smem + 36864);     // [64][136]
    bf16_t* sS  = (bf16_t*)(smem + 54272);     // [64][72]
    float*  wpS = (float*)(smem + 63488);      // [128] decay powers
    bf16_t* Sst = kS;
    bf16_t* att_s = kS;
    const int bid = blockIdx.x;
    const int h = bid & 31, n = (bid>>5)&15, b = bid>>9;
    const int tid = threadIdx.x;
    const int wave = tid>>6, lane = tid&63, quad = lane>>4, l15 = lane&15;
    const size_t row0 = (size_t)b*SEQ + n*CHUNK;
    const int col0 = h*D_HEAD;
    const float lnw = -__expf(td[h]);
    const float u   =  __expf(tf[h]);
    if (tid < 128) wpS[tid] = __expf(lnw * (float)tid);
    for (int it=0; it<4; ++it){
        int idx = tid + it*256;
        int row = idx>>3, c8 = (idx&7)*8;
        *(bf16x8*)&rS[row*72 + c8] = *(const bf16x8*)&rb[(row0+row)*D_MODEL + col0 + c8];
        *(bf16x8*)&kS[row*72 + c8] = *(const bf16x8*)&kb[(row0+row)*D_MODEL + col0 + c8];
        bf16x8 vv = *(const bf16x8*)&vb[(row0+row)*D_MODEL + col0 + c8];
        for (int q=0;q<8;++q) vT[(c8+q)*136 + row] = vv[q];
    }
    // state staged transposed: sS[d][e] = stg[e][d]
    const bf16_t* stg = stT + (size_t)bid*4096;
    for (int it=0; it<2; ++it){
        int idx = tid + it*256;
        int row = idx>>3, c8 = (idx&7)*8;       // row = e, c8.. = d
        bf16x8 sv = *(const bf16x8*)&stg[row*64 + c8];
        for (int q=0;q<8;++q) sS[(c8+q)*72 + row] = sv[q];
    }
    __syncthreads();
    // --- S = r k^T (full 128x128 in registers)
    f32x4 accS[2][8];
    for (int i=0;i<2;++i) for (int j=0;j<8;++j) accS[i][j] = (f32x4){0.f,0.f,0.f,0.f};
    for (int kk=0; kk<2; ++kk){
        bf16x8 af[2], bfr[8];
        for (int i=0;i<2;++i) af[i] = *(const bf16x8*)&rS[(wave*32+i*16+l15)*72 + kk*32 + quad*8];
        for (int j=0;j<8;++j) bfr[j] = *(const bf16x8*)&kS[(j*16+l15)*72 + kk*32 + quad*8];
        for (int i=0;i<2;++i) for (int j=0;j<8;++j)
            accS[i][j] = __builtin_amdgcn_mfma_f32_16x16x32_bf16(af[i], bfr[j], accS[i][j], 0,0,0);
    }
    __syncthreads();   // kS dead; Sst overlays it
    // --- P = (S*mask) v, staged 32 columns at a time
    f32x4 accP[2][4];
    for (int i=0;i<2;++i) for (int j=0;j<4;++j) accP[i][j] = (f32x4){0.f,0.f,0.f,0.f};
    for (int kk=0; kk<4; ++kk){
        for (int i=0;i<2;++i) for (int jj=0;jj<2;++jj) for (int e=0;e<4;++e){
            int si = wave*32 + i*16 + quad*4 + e;
            int sj = kk*32 + jj*16 + l15;
            float m;
            if (si > sj)       m = wpS[si-sj-1];
            else if (si == sj) m = u;
            else               m = 0.f;
            Sst[si*40 + jj*16 + l15] = (bf16_t)(accS[i][kk*2+jj][e] * m);
        }
        __syncthreads();
        bf16x8 af[2], bfr[4];
        for (int i=0;i<2;++i) af[i] = *(const bf16x8*)&Sst[(wave*32+i*16+l15)*40 + quad*8];
        for (int j=0;j<4;++j) bfr[j] = *(const bf16x8*)&vT[(j*16+l15)*136 + kk*32 + quad*8];
        for (int i=0;i<2;++i) for (int j=0;j<4;++j)
            accP[i][j] = __builtin_amdgcn_mfma_f32_16x16x32_bf16(af[i], bfr[j], accP[i][j], 0,0,0);
        __syncthreads();
    }
    // --- bias = r @ state (state staged transposed: sS[d][e])
    f32x4 accB[2][4];
    for (int i=0;i<2;++i) for (int j=0;j<4;++j) accB[i][j] = (f32x4){0.f,0.f,0.f,0.f};
    for (int kk=0; kk<2; ++kk){
        bf16x8 af[2], bfr[4];
        for (int i=0;i<2;++i) af[i] = *(const bf16x8*)&rS[(wave*32+i*16+l15)*72 + kk*32 + quad*8];
        for (int j=0;j<4;++j) bfr[j] = *(const bf16x8*)&sS[(j*16+l15)*72 + kk*32 + quad*8];
        for (int i=0;i<2;++i) for (int j=0;j<4;++j)
            accB[i][j] = __builtin_amdgcn_mfma_f32_16x16x32_bf16(af[i], bfr[j], accB[i][j], 0,0,0);
    }
    // --- combine + in-register LayerNorm over d
    float pre[2][4][4];
    float mu_r[2][4], rs_r[2][4];
    for (int i=0;i<2;++i) for (int e=0;e<4;++e){
        int si = wave*32 + i*16 + quad*4 + e;
        float wsi = wpS[si];
        float s = 0.f, q2 = 0.f;
        for (int j=0;j<4;++j){
            float v = accP[i][j][e] + accB[i][j][e]*wsi;
            pre[i][j][e] = v;
            s += v; q2 += v*v;
        }
        for (int o=1;o<16;o<<=1){ s += __shfl_xor(s,o,64); q2 += __shfl_xor(q2,o,64); }
        float mu = s*(1.f/64.f);
        float var = q2*(1.f/64.f) - mu*mu;
        mu_r[i][e] = mu; rs_r[i][e] = rsqrtf(var + LN_EPS);
    }
    float gxv[4], bxv[4];
    for (int j=0;j<4;++j){ gxv[j] = gx[col0 + j*16 + l15]; bxv[j] = bx[col0 + j*16 + l15]; }
    for (int i=0;i<2;++i) for (int j=0;j<4;++j) for (int e=0;e<4;++e){
        int si = wave*32 + i*16 + quad*4 + e;
        att_s[si*72 + j*16 + l15] = (bf16_t)((pre[i][j][e]-mu_r[i][e])*rs_r[i][e]*gxv[j] + bxv[j]);
    }
    __syncthreads();
    for (int it=0; it<4; ++it){
        int idx = tid + it*256;
        int row = idx>>3, c8 = (idx&7)*8;
        *(bf16x8*)&att[(row0+row)*D_MODEL + col0 + c8] = *(const bf16x8*)&att_s[row*72 + c8];
    }
}

// ---------------------------------------------------------------------------
// Launch. Workspace (>= 224 MiB), aliasing:
//   [0,32)    rxb bf16   -> U f32 (after rkv GEMM)
//   [32,64)   kxb bf16   -> stT bf16
//   [64,96)   vxb bf16   -> att bf16
//   [96,128)  WT[4] bf16 (Wr,Wk,Wv,Wo transposed; Wo alive to end)
//   [128,160) rb, [160,192) kb, [192,224) vb
// ---------------------------------------------------------------------------
extern "C" void kernel_launch(void* const* d_in, const int* in_sizes, int n_in,
                              void* d_out, int out_size, void* d_ws, size_t ws_size,
                              hipStream_t stream) {
    const float* x   = (const float*)d_in[0];
    const float* tmr = (const float*)d_in[1];
    const float* tmk = (const float*)d_in[2];
    const float* tmv = (const float*)d_in[3];
    const float* Wk  = (const float*)d_in[4];
    const float* Wv  = (const float*)d_in[5];
    const float* Wr  = (const float*)d_in[6];
    const float* Wo  = (const float*)d_in[7];
    const float* td  = (const float*)d_in[8];
    const float* tf  = (const float*)d_in[9];
    const float* g1  = (const float*)d_in[10];
    const float* b1  = (const float*)d_in[11];
    const float* gx  = (const float*)d_in[12];
    const float* bx  = (const float*)d_in[13];

    float* out0 = (float*)d_out;
    float* out1 = out0 + (size_t)NTOK*D_MODEL;
    float* out2 = out1 + (size_t)BZ*D_MODEL;

    const size_t MB = 1ull<<20;
    char* ws = (char*)d_ws;
    bf16_t* rxb = (bf16_t*)(ws);
    bf16_t* kxb = (bf16_t*)(ws + 32*MB);
    bf16_t* vxb = (bf16_t*)(ws + 64*MB);
    bf16_t* WTb = (bf16_t*)(ws + 96*MB);          // 4 x 8MB: Wr,Wk,Wv,Wo
    bf16_t* WoT = (bf16_t*)(ws + 120*MB);
    bf16_t* rb  = (bf16_t*)(ws + 128*MB);
    float*  U   = (float*)(ws);                   // after rxb dead
    bf16_t* stT = (bf16_t*)(ws + 32*MB);          // after kxb dead
    bf16_t* att = (bf16_t*)(ws + 64*MB);          // after vxb dead
    bf16_t* kb  = (bf16_t*)(ws + 160*MB);
    bf16_t* vb  = (bf16_t*)(ws + 192*MB);

    k_ln_mix<<<NTOK, 256, 0, stream>>>(x, tmr, tmk, tmv, g1, b1, rxb, kxb, vxb, out1);

    dim3 gT(32, 32, 4);
    k_wt4<<<gT, 256, 0, stream>>>(Wr, Wk, Wv, Wo, WTb);

    dim3 gG3(D_MODEL/256, NTOK/256, 3);   // (8, 32, 3)
    k_gemm_rkv<<<gG3, 512, 0, stream>>>(rxb, WTb, rb);

    const int nblk = BZ*NC*N_HEADS;   // 2048
    k_chunk_U <<<nblk, 256, 0, stream>>>(kb, vb, td, U);
    k_scan    <<<256, 256, 0, stream>>>(U, td, stT, out2);
    k_att_fused<<<nblk, 256, 0, stream>>>(rb, kb, vb, stT, td, tf, gx, bx, att);

    dim3 gG(D_MODEL/256, NTOK/256);       // (8, 32)
    k_gemm_out<<<gG, 512, 0, stream>>>(att, WoT, out0, x);
}

// Round 5
// 545.165 us; speedup vs baseline: 1.0316x; 1.0183x over previous
//
#include <hip/hip_runtime.h>

#define D_MODEL 2048
#define N_HEADS 32
#define D_HEAD  64
#define CHUNK   128
#define SEQ     2048
#define BZ      4
#define NC      16            // SEQ/CHUNK
#define NTOK    (BZ*SEQ)      // 8192
#define LN_EPS  1e-5f

typedef __bf16 bf16_t;
typedef bf16_t bf16x8 __attribute__((ext_vector_type(8)));
typedef float  f32x4  __attribute__((ext_vector_type(4)));

#define GLOBAL_AS __attribute__((address_space(1)))
#define LDS_AS    __attribute__((address_space(3)))

// ---------------------------------------------------------------------------
// K1: LayerNorm + token-shift time-mix -> rx,kx,vx (bf16). Also writes
// xn[:, -1, :] (output 1).
// ---------------------------------------------------------------------------
__global__ __launch_bounds__(256) void k_ln_mix(
    const float* __restrict__ x, const float* __restrict__ tmr,
    const float* __restrict__ tmk, const float* __restrict__ tmv,
    const float* __restrict__ g1, const float* __restrict__ b1,
    bf16_t* __restrict__ rxb, bf16_t* __restrict__ kxb, bf16_t* __restrict__ vxb,
    float* __restrict__ xn_last)
{
    __shared__ float sbuf[16];
    const int row = blockIdx.x;
    const int t = row & (SEQ-1);
    const int tid = threadIdx.x;
    const float4* xc4 = (const float4*)(x + (size_t)row*D_MODEL);
    float4 c0 = xc4[tid*2], c1 = xc4[tid*2+1];
    float4 p0 = {0,0,0,0}, p1 = {0,0,0,0};
    const bool hasprev = (t != 0);
    if (hasprev){
        const float4* xp4 = (const float4*)(x + (size_t)(row-1)*D_MODEL);
        p0 = xp4[tid*2]; p1 = xp4[tid*2+1];
    }
    float xc[8] = {c0.x,c0.y,c0.z,c0.w,c1.x,c1.y,c1.z,c1.w};
    float xp[8] = {p0.x,p0.y,p0.z,p0.w,p1.x,p1.y,p1.z,p1.w};
    float sc=0.f, qc=0.f, sp=0.f, qp=0.f;
    for (int q=0;q<8;++q){ sc+=xc[q]; qc+=xc[q]*xc[q]; sp+=xp[q]; qp+=xp[q]*xp[q]; }
    for (int o=1;o<64;o<<=1){
        sc += __shfl_xor(sc,o,64); qc += __shfl_xor(qc,o,64);
        sp += __shfl_xor(sp,o,64); qp += __shfl_xor(qp,o,64);
    }
    const int wave = tid>>6, lane = tid&63;
    if (lane==0){ sbuf[wave*4+0]=sc; sbuf[wave*4+1]=qc; sbuf[wave*4+2]=sp; sbuf[wave*4+3]=qp; }
    __syncthreads();
    sc = sbuf[0]+sbuf[4]+sbuf[8]+sbuf[12];
    qc = sbuf[1]+sbuf[5]+sbuf[9]+sbuf[13];
    sp = sbuf[2]+sbuf[6]+sbuf[10]+sbuf[14];
    qp = sbuf[3]+sbuf[7]+sbuf[11]+sbuf[15];
    const float inv = 1.f/(float)D_MODEL;
    float muc = sc*inv, varc = qc*inv - muc*muc;
    float rc  = rsqrtf(varc + LN_EPS);
    float mup = sp*inv, varp = qp*inv - mup*mup;
    float rp  = rsqrtf(varp + LN_EPS);
    bf16x8 rv, kv, vv;
    const int ci = tid*8;
    float xnl[8];
    for (int q=0;q<8;++q){
        int c = ci+q;
        float gg = g1[c], bb = b1[c];
        float xn = (xc[q]-muc)*rc*gg + bb;
        float sh = hasprev ? ((xp[q]-mup)*rp*gg + bb) : 0.f;
        float mr = tmr[c], mk = tmk[c], mv = tmv[c];
        rv[q] = (bf16_t)(xn*mr + (1.f-mr)*sh);
        kv[q] = (bf16_t)(xn*mk + (1.f-mk)*sh);
        vv[q] = (bf16_t)(xn*mv + (1.f-mv)*sh);
        xnl[q] = xn;
    }
    size_t base = (size_t)row*D_MODEL + ci;
    *(bf16x8*)&rxb[base] = rv;
    *(bf16x8*)&kxb[base] = kv;
    *(bf16x8*)&vxb[base] = vv;
    if (t == SEQ-1){
        int b = row >> 11;
        for (int q=0;q<8;++q) xn_last[(size_t)b*D_MODEL + ci + q] = xnl[q];
    }
}

// ---------------------------------------------------------------------------
// K2: batched transpose + f32->bf16: WT[z][n][k] = W_z[k][n].
// ---------------------------------------------------------------------------
__global__ __launch_bounds__(256) void k_wt4(
    const float* __restrict__ W0, const float* __restrict__ W1,
    const float* __restrict__ W2, const float* __restrict__ W3,
    bf16_t* __restrict__ WTbase)
{
    __shared__ float tile[64][65];
    const int z = blockIdx.z;
    const float* W = (z==0)?W0:(z==1)?W1:(z==2)?W2:W3;
    bf16_t* WT = WTbase + (size_t)z*D_MODEL*D_MODEL;
    const int n0 = blockIdx.x*64, k0 = blockIdx.y*64;
    const int j = threadIdx.x & 63, i0 = threadIdx.x >> 6;
    for (int it=0; it<16; ++it){
        int i = i0 + it*4;
        tile[j][i] = W[(size_t)(k0+i)*D_MODEL + n0 + j];
    }
    __syncthreads();
    for (int it=0; it<16; ++it){
        int idx = threadIdx.x + it*256;
        int r = idx >> 6, c = idx & 63;
        WT[(size_t)(n0+r)*D_MODEL + k0 + c] = (bf16_t)tile[r][c];
    }
}

// ---------------------------------------------------------------------------
// XCD-aware swizzle for an (8, 32) tile grid.
// ---------------------------------------------------------------------------
__device__ __forceinline__ void xcd_swizzle_8x32(int& bx, int& by)
{
    int id = blockIdx.y*8 + blockIdx.x;      // [0,256)
    int p  = id & 7;
    int n  = id >> 3;                        // per-XCD sequence index [0,32)
    bx = n & 7;
    by = (p<<2) | (n>>3);
}

// ---------------------------------------------------------------------------
// 256x256 8-phase bf16 GEMM core (best measured config, kept from r4):
// frag prefetch one phase ahead + in-region SGB interleave + counted vmcnt.
// ---------------------------------------------------------------------------
__device__ __forceinline__ bf16x8 ldfrag(const char* regn, int ks, int row, int quad)
{
    return *(const bf16x8*)(regn + ks*16384 + row*64 + (((quad ^ (row>>1)) & 3) << 4));
}

#define GLD(gp, lp) __builtin_amdgcn_global_load_lds((const GLOBAL_AS void*)(gp), (LDS_AS void*)(lp), 16, 0, 0)
#define STAGE2(gp, lb) do{ GLD((gp), (lb)+tid16); GLD((gp)+rowskip, (lb)+8192+tid16); }while(0)
#define BARX() do{ asm volatile("" ::: "memory"); __builtin_amdgcn_s_barrier(); asm volatile("" ::: "memory"); }while(0)
#define WAITV(n) asm volatile("s_waitcnt vmcnt(" #n ")" ::: "memory")
#define PFA(dst, buf, ks) do{ _Pragma("unroll") \
    for (int mf=0;mf<4;++mf) dst[mf] = ldfrag((buf), (ks), wrow+mf*16+l15, quad); }while(0)
#define PFB(dst, buf, ks, off) do{ _Pragma("unroll") \
    for (int nf=0;nf<4;++nf) dst[nf] = ldfrag((buf), (ks), wcol+(off)+nf*16+l15, quad); }while(0)
#define MMX(AV, BV, CH) do{ \
    _Pragma("unroll") for (int mf=0;mf<4;++mf){ \
    _Pragma("unroll") for (int nf=0;nf<4;++nf)  \
        acc[mf][(CH)*4+nf] = __builtin_amdgcn_mfma_f32_16x16x32_bf16( \
            AV[mf], BV[nf], acc[mf][(CH)*4+nf], 0,0,0); } }while(0)
#define SGB(m,n) __builtin_amdgcn_sched_group_barrier((m),(n),0)
#define SGB_PH4() do{ _Pragma("unroll") for (int s_=0;s_<4;++s_){ SGB(0x008,4); SGB(0x100,1);} }while(0)
#define SGB_PH8() do{ _Pragma("unroll") for (int s_=0;s_<8;++s_){ SGB(0x008,2); SGB(0x100,1);} }while(0)

template<int OUT_BF16>
__device__ __forceinline__ void gemm256_core(
    const bf16_t* __restrict__ A, const bf16_t* __restrict__ B,
    void* __restrict__ Cout, const float* __restrict__ resid,
    const int N, const int K, char* smem, int bx, int by)
{
    const int tid = threadIdx.x;
    const int lane = tid&63, quad = lane>>4, l15 = lane&15;
    const int wave = tid>>6;
    const int wm = wave>>1, wn = wave&1;         // 4x2 wave grid
    const int wrow = wm*64, wcol = wn*128;       // per-wave C = 64x128
    const int arow0 = by*256, bcol0 = bx*256;
    const int NT = K>>6;
    const int K2 = K*2;
    const int tid16 = tid*16;

    const int rr  = tid>>2;
    const int kcb = (((tid&3) ^ ((tid>>3)&3)) << 4);
    const char* Ag = (const char*)A + (size_t)(arow0 + rr)*K2 + kcb;
    const char* Bg = (const char*)B + (size_t)(bcol0 + rr)*K2 + kcb;
    const int rowskip = 128*K2;

    char* A0 = smem;             char* B0 = smem + 32768;
    char* A1 = smem + 65536;     char* B1 = smem + 98304;

    // prologue: Ak0(0) Bk0(0) Ak1(0) Bk1(0) Ak0(1)  (10 loads)
    STAGE2(Ag,       A0);
    STAGE2(Bg,       B0);
    STAGE2(Ag + 64,  A0 + 16384);
    STAGE2(Bg + 64,  B0 + 16384);
    STAGE2(Ag + 128, A1);
    WAITV(6);                                  // Ak0(0), Bk0(0) retired
    BARX();

    f32x4 acc[4][8];
    #pragma unroll
    for (int i=0;i<4;++i)
        #pragma unroll
        for (int j=0;j<8;++j) acc[i][j] = (f32x4){0.f,0.f,0.f,0.f};

    bf16x8 aP[4], aQ[4], bP[4], bQ[4];
    PFA(aP, A0, 0);            // a ks0, tile 0
    PFB(bP, B0, 0, 0);         // b ks0 ch0, tile 0

    #pragma unroll 2
    for (int t=0; t<NT; ++t){
        const char* As = (t&1) ? A1 : A0;
        const char* Bs = (t&1) ? B1 : B0;
        char* An = (t&1) ? A0 : A1;
        char* Bn = (t&1) ? B0 : B1;
        char* Ac = (t&1) ? A1 : A0;
        const int tn  = (t+1 < NT) ? t+1 : NT-1;
        const int tn2 = (t+2 < NT) ? t+2 : NT-1;
        const char* gA1 = Ag + tn*128;
        const char* gB1 = Bg + tn*128;
        const char* gA2 = Ag + tn2*128;

        // ---- phase 0: MFMA (ks0, ch0) with aP,bP; prefetch bQ = ks0 ch1
        STAGE2(gB1, Bn);                       // Bk0(t+1)
        BARX();
        __builtin_amdgcn_s_setprio(1);
        MMX(aP, bP, 0);
        PFB(bQ, Bs, 0, 64);
        SGB_PH4();
        __builtin_amdgcn_s_setprio(0);
        BARX();
        // ---- phase 1: MFMA (ks0, ch1); prefetch aQ = ks1 A, bP = ks1 ch0
        STAGE2(gA1 + 64, An + 16384);          // Ak1(t+1)
        WAITV(6);
        BARX();
        __builtin_amdgcn_s_setprio(1);
        MMX(aP, bQ, 1);
        PFA(aQ, As, 1);
        PFB(bP, Bs, 1, 0);
        SGB_PH8();
        __builtin_amdgcn_s_setprio(0);
        BARX();
        // ---- phase 2: MFMA (ks1, ch0); prefetch bQ = ks1 ch1
        STAGE2(gB1 + 64, Bn + 16384);          // Bk1(t+1)
        BARX();
        __builtin_amdgcn_s_setprio(1);
        MMX(aQ, bP, 0);
        PFB(bQ, Bs, 1, 64);
        SGB_PH4();
        __builtin_amdgcn_s_setprio(0);
        BARX();
        // ---- phase 3: MFMA (ks1, ch1); prefetch next tile's aP, bP
        STAGE2(gA2, Ac);                       // Ak0(t+2) -> current buf (dead)
        WAITV(6);                              // retires Ak0(t+1), Bk0(t+1)
        BARX();
        __builtin_amdgcn_s_setprio(1);
        MMX(aQ, bQ, 1);
        PFA(aP, An, 0);
        PFB(bP, Bn, 0, 0);
        SGB_PH8();
        __builtin_amdgcn_s_setprio(0);
        BARX();
    }
    WAITV(0);
    __syncthreads();

    if (OUT_BF16){
        bf16_t* Cb = (bf16_t*)Cout;
        bf16_t* Rp = (bf16_t*)smem;            // [256][136]
        #pragma unroll
        for (int jh=0; jh<2; ++jh){
            if (wn == jh){
                #pragma unroll
                for (int mf=0;mf<4;++mf)
                    #pragma unroll
                    for (int nf=0;nf<8;++nf)
                        #pragma unroll
                        for (int e=0;e<4;++e){
                            int rrow = wrow + mf*16 + quad*4 + e;
                            Rp[rrow*136 + nf*16 + l15] = (bf16_t)acc[mf][nf][e];
                        }
            }
            __syncthreads();
            for (int it=0; it<8; ++it){
                int idx = tid + it*512;
                int row = idx >> 4, c8 = (idx & 15)*8;
                *(bf16x8*)&Cb[(size_t)(arow0+row)*N + bcol0 + jh*128 + c8] =
                    *(const bf16x8*)&Rp[row*136 + c8];
            }
            __syncthreads();
        }
    } else {
        float* C = (float*)Cout;
        #pragma unroll
        for (int mf=0;mf<4;++mf)
            #pragma unroll
            for (int nf=0;nf<8;++nf)
                #pragma unroll
                for (int e=0;e<4;++e){
                    size_t r = (size_t)(arow0 + wrow + mf*16 + quad*4 + e);
                    size_t c = (size_t)(bcol0 + wcol + nf*16 + l15);
                    C[r*N + c] = resid[r*N + c] + acc[mf][nf][e];
                }
    }
}

// batched r/k/v GEMM: z selects A/B/C by fixed stride
__global__ __launch_bounds__(512, 2) void k_gemm_rkv(
    const bf16_t* __restrict__ Abase, const bf16_t* __restrict__ Bbase,
    bf16_t* __restrict__ Cbase)
{
    __shared__ __align__(16) char smem[131072];
    const int z = blockIdx.z;
    const bf16_t* A = Abase + (size_t)z*NTOK*D_MODEL;
    const bf16_t* B = Bbase + (size_t)z*D_MODEL*D_MODEL;
    bf16_t*       C = Cbase + (size_t)z*NTOK*D_MODEL;
    int bx, by; xcd_swizzle_8x32(bx, by);
    gemm256_core<1>(A, B, (void*)C, nullptr, D_MODEL, D_MODEL, smem, bx, by);
}

__global__ __launch_bounds__(512, 2) void k_gemm_out(
    const bf16_t* __restrict__ A, const bf16_t* __restrict__ B,
    float* __restrict__ C, const float* __restrict__ resid)
{
    __shared__ __align__(16) char smem[131072];
    int bx, by; xcd_swizzle_8x32(bx, by);
    gemm256_core<0>(A, B, (void*)C, resid, D_MODEL, D_MODEL, smem, bx, by);
}

// ---------------------------------------------------------------------------
// K4b: per (b,chunk,h): U[e][d] = sum_j k[j][e] * w^(C-1-j) * v[j][d]
// Column-scatter transpose writes are XOR-swizzled: without it, each 8-lane
// group's writes land on ONE bank (stride 8*136 elem == 0 mod 32 dwords) ->
// 8-way conflict on 16k scalar writes/block. row' = row ^ ((col>>3&7)<<3)
// spreads them over all 32 banks (2 lanes/bank = free); reads apply the
// same XOR (8-elem aligned, so ds_read_b128 stays legal).
// ---------------------------------------------------------------------------
__global__ __launch_bounds__(256) void k_chunk_U(
    const bf16_t* __restrict__ kb, const bf16_t* __restrict__ vb,
    const float* __restrict__ td, float* __restrict__ U)
{
    __shared__ __align__(16) bf16_t kT[64*136];
    __shared__ __align__(16) bf16_t vT[64*136];
    const int bid = blockIdx.x;
    const int h = bid & 31, n = (bid>>5)&15, b = bid>>9;
    const int tid = threadIdx.x;
    const int wave = tid>>6, lane = tid&63, quad = lane>>4, l15 = lane&15;
    const size_t row0 = (size_t)b*SEQ + n*CHUNK;
    const int col0 = h*D_HEAD;
    const float lnw = -__expf(td[h]);
    for (int it=0; it<4; ++it){
        int idx = tid + it*256;
        int row = idx>>3, c8 = (idx&7)*8;
        float wj = __expf(lnw * (float)(CHUNK-1-row));
        bf16x8 kv = *(const bf16x8*)&kb[(row0+row)*D_MODEL + col0 + c8];
        bf16x8 vv = *(const bf16x8*)&vb[(row0+row)*D_MODEL + col0 + c8];
        for (int q=0;q<8;++q){
            int col = c8 + q;
            int rw  = row ^ (((col>>3)&7)<<3);
            kT[col*136 + rw] = (bf16_t)((float)kv[q] * wj);
            vT[col*136 + rw] = vv[q];
        }
    }
    __syncthreads();
    f32x4 accU[4];
    for (int j=0;j<4;++j) accU[j] = (f32x4){0.f,0.f,0.f,0.f};
    for (int kk=0; kk<4; ++kk){
        int ea  = wave*16 + l15;
        int rba = (kk*32 + quad*8) ^ (((ea>>3)&7)<<3);
        bf16x8 af = *(const bf16x8*)&kT[ea*136 + rba];
        bf16x8 bfr[4];
        for (int j=0;j<4;++j){
            int eb  = j*16 + l15;
            int rbb = (kk*32 + quad*8) ^ (((eb>>3)&7)<<3);
            bfr[j] = *(const bf16x8*)&vT[eb*136 + rbb];
        }
        for (int j=0;j<4;++j)
            accU[j] = __builtin_amdgcn_mfma_f32_16x16x32_bf16(af, bfr[j], accU[j], 0,0,0);
    }
    float* Ub = U + (size_t)bid*(D_HEAD*D_HEAD);
    for (int j=0;j<4;++j) for (int e=0;e<4;++e){
        int ei = wave*16 + quad*4 + e;
        int d  = j*16 + l15;
        Ub[ei*D_HEAD + d] = accU[j][e];
    }
}

// ---------------------------------------------------------------------------
// K5: sequential prefix over chunks. Per-element independent scan ->
// 256 blocks x 256 threads x 8 elements, fully coalesced (bf16x8 / float4).
// ---------------------------------------------------------------------------
__global__ __launch_bounds__(256) void k_scan(
    const float* __restrict__ U, const float* __restrict__ td,
    bf16_t* __restrict__ stT, float* __restrict__ outState)
{
    const int blk = blockIdx.x;          // 256 = 128 bh x 2 slices
    const int bh = blk >> 1, sl = blk & 1;
    const int h = bh & 31, b = bh >> 5;
    const int f8 = (sl*256 + threadIdx.x)*8;   // [0,4096)
    const float lnw = -__expf(td[h]);
    const float wC  =  __expf(lnw * (float)CHUNK);
    float st[8];
    #pragma unroll
    for (int q=0;q<8;++q) st[q] = 0.f;
    for (int n=0;n<NC;++n){
        size_t base = ((size_t)((b*NC + n)*N_HEADS + h))*4096;
        bf16x8 s8;
        #pragma unroll
        for (int q=0;q<8;++q) s8[q] = (bf16_t)st[q];
        *(bf16x8*)&stT[base + f8] = s8;
        float4 u0 = *(const float4*)&U[base + f8];
        float4 u1 = *(const float4*)&U[base + f8 + 4];
        float uu[8] = {u0.x,u0.y,u0.z,u0.w,u1.x,u1.y,u1.z,u1.w};
        #pragma unroll
        for (int q=0;q<8;++q) st[q] = st[q]*wC + uu[q];
    }
    size_t ob = ((size_t)(b*N_HEADS + h))*4096 + f8;
    #pragma unroll
    for (int q=0;q<8;++q) outState[ob + q] = st[q];
}

// ---------------------------------------------------------------------------
// K6: fused per (b,chunk,h): S=(r k^T)*mask -> P=S v -> bias=(r state)*w^i ->
// LN over d_head -> att bf16.
//   - vT/sS column-scatter transposes XOR-swizzled (same scheme as K4b).
//   - mask via a 256-entry LDS table tab[128+si-sj] (0 / u / w^(d-1)):
//     removes the divergent 3-way branch per element.
// ---------------------------------------------------------------------------
__global__ __launch_bounds__(256) void k_att_fused(
    const bf16_t* __restrict__ rb, const bf16_t* __restrict__ kb, const bf16_t* __restrict__ vb,
    const bf16_t* __restrict__ stT, const float* __restrict__ td, const float* __restrict__ tf,
    const float* __restrict__ gx, const float* __restrict__ bx,
    bf16_t* __restrict__ att)
{
    __shared__ __align__(16) char smem[65024];
    bf16_t* rS  = (bf16_t*)smem;               // [128][72]
    bf16_t* kS  = (bf16_t*)(smem + 18432);     // [128][72]; later Sst [128][40], att_s [128][72]
    bf16_t* vT  = (bf16_t*)(smem + 36864);     // [64][136] (swizzled rows)
    bf16_t* sS  = (bf16_t*)(smem + 54272);     // [64][72]  (swizzled rows)
    float*  wpS = (float*)(smem + 63488);      // [128] decay powers
    float*  tabS= (float*)(smem + 64000);      // [256] mask table
    bf16_t* Sst = kS;
    bf16_t* att_s = kS;
    const int bid = blockIdx.x;
    const int h = bid & 31, n = (bid>>5)&15, b = bid>>9;
    const int tid = threadIdx.x;
    const int wave = tid>>6, lane = tid&63, quad = lane>>4, l15 = lane&15;
    const size_t row0 = (size_t)b*SEQ + n*CHUNK;
    const int col0 = h*D_HEAD;
    const float lnw = -__expf(td[h]);
    const float u   =  __expf(tf[h]);
    if (tid < 128) wpS[tid] = __expf(lnw * (float)tid);
    tabS[tid] = (tid < 128) ? 0.f : (tid == 128 ? u : __expf(lnw * (float)(tid-129)));
    for (int it=0; it<4; ++it){
        int idx = tid + it*256;
        int row = idx>>3, c8 = (idx&7)*8;
        *(bf16x8*)&rS[row*72 + c8] = *(const bf16x8*)&rb[(row0+row)*D_MODEL + col0 + c8];
        *(bf16x8*)&kS[row*72 + c8] = *(const bf16x8*)&kb[(row0+row)*D_MODEL + col0 + c8];
        bf16x8 vv = *(const bf16x8*)&vb[(row0+row)*D_MODEL + col0 + c8];
        for (int q=0;q<8;++q){
            int d  = c8 + q;
            int rw = row ^ (((d>>3)&7)<<3);
            vT[d*136 + rw] = vv[q];
        }
    }
    // state staged transposed: sS[d][e] = stg[e][d], swizzled second index
    const bf16_t* stg = stT + (size_t)bid*4096;
    for (int it=0; it<2; ++it){
        int idx = tid + it*256;
        int row = idx>>3, c8 = (idx&7)*8;       // row = e, c8.. = d
        bf16x8 sv = *(const bf16x8*)&stg[row*64 + c8];
        for (int q=0;q<8;++q){
            int d  = c8 + q;
            int ew = row ^ (((d>>3)&7)<<3);
            sS[d*72 + ew] = sv[q];
        }
    }
    __syncthreads();
    // --- S = r k^T (full 128x128 in registers)
    f32x4 accS[2][8];
    for (int i=0;i<2;++i) for (int j=0;j<8;++j) accS[i][j] = (f32x4){0.f,0.f,0.f,0.f};
    for (int kk=0; kk<2; ++kk){
        bf16x8 af[2], bfr[8];
        for (int i=0;i<2;++i) af[i] = *(const bf16x8*)&rS[(wave*32+i*16+l15)*72 + kk*32 + quad*8];
        for (int j=0;j<8;++j) bfr[j] = *(const bf16x8*)&kS[(j*16+l15)*72 + kk*32 + quad*8];
        for (int i=0;i<2;++i) for (int j=0;j<8;++j)
            accS[i][j] = __builtin_amdgcn_mfma_f32_16x16x32_bf16(af[i], bfr[j], accS[i][j], 0,0,0);
    }
    __syncthreads();   // kS dead; Sst overlays it
    // --- P = (S*mask) v, staged 32 columns at a time
    f32x4 accP[2][4];
    for (int i=0;i<2;++i) for (int j=0;j<4;++j) accP[i][j] = (f32x4){0.f,0.f,0.f,0.f};
    for (int kk=0; kk<4; ++kk){
        for (int i=0;i<2;++i) for (int jj=0;jj<2;++jj) for (int e=0;e<4;++e){
            int si = wave*32 + i*16 + quad*4 + e;
            int sj = kk*32 + jj*16 + l15;
            float m = tabS[128 + si - sj];
            Sst[si*40 + jj*16 + l15] = (bf16_t)(accS[i][kk*2+jj][e] * m);
        }
        __syncthreads();
        bf16x8 af[2], bfr[4];
        for (int i=0;i<2;++i) af[i] = *(const bf16x8*)&Sst[(wave*32+i*16+l15)*40 + quad*8];
        for (int j=0;j<4;++j){
            int d  = j*16 + l15;
            int rb2 = (kk*32 + quad*8) ^ (((d>>3)&7)<<3);
            bfr[j] = *(const bf16x8*)&vT[d*136 + rb2];
        }
        for (int i=0;i<2;++i) for (int j=0;j<4;++j)
            accP[i][j] = __builtin_amdgcn_mfma_f32_16x16x32_bf16(af[i], bfr[j], accP[i][j], 0,0,0);
        __syncthreads();
    }
    // --- bias = r @ state (state staged transposed: sS[d][e], swizzled)
    f32x4 accB[2][4];
    for (int i=0;i<2;++i) for (int j=0;j<4;++j) accB[i][j] = (f32x4){0.f,0.f,0.f,0.f};
    for (int kk=0; kk<2; ++kk){
        bf16x8 af[2], bfr[4];
        for (int i=0;i<2;++i) af[i] = *(const bf16x8*)&rS[(wave*32+i*16+l15)*72 + kk*32 + quad*8];
        for (int j=0;j<4;++j){
            int d  = j*16 + l15;
            int eb = (kk*32 + quad*8) ^ (((d>>3)&7)<<3);
            bfr[j] = *(const bf16x8*)&sS[d*72 + eb];
        }
        for (int i=0;i<2;++i) for (int j=0;j<4;++j)
            accB[i][j] = __builtin_amdgcn_mfma_f32_16x16x32_bf16(af[i], bfr[j], accB[i][j], 0,0,0);
    }
    // --- combine + in-register LayerNorm over d
    float pre[2][4][4];
    float mu_r[2][4], rs_r[2][4];
    for (int i=0;i<2;++i) for (int e=0;e<4;++e){
        int si = wave*32 + i*16 + quad*4 + e;
        float wsi = wpS[si];
        float s = 0.f, q2 = 0.f;
        for (int j=0;j<4;++j){
            float v = accP[i][j][e] + accB[i][j][e]*wsi;
            pre[i][j][e] = v;
            s += v; q2 += v*v;
        }
        for (int o=1;o<16;o<<=1){ s += __shfl_xor(s,o,64); q2 += __shfl_xor(q2,o,64); }
        float mu = s*(1.f/64.f);
        float var = q2*(1.f/64.f) - mu*mu;
        mu_r[i][e] = mu; rs_r[i][e] = rsqrtf(var + LN_EPS);
    }
    float gxv[4], bxv[4];
    for (int j=0;j<4;++j){ gxv[j] = gx[col0 + j*16 + l15]; bxv[j] = bx[col0 + j*16 + l15]; }
    for (int i=0;i<2;++i) for (int j=0;j<4;++j) for (int e=0;e<4;++e){
        int si = wave*32 + i*16 + quad*4 + e;
        att_s[si*72 + j*16 + l15] = (bf16_t)((pre[i][j][e]-mu_r[i][e])*rs_r[i][e]*gxv[j] + bxv[j]);
    }
    __syncthreads();
    for (int it=0; it<4; ++it){
        int idx = tid + it*256;
        int row = idx>>3, c8 = (idx&7)*8;
        *(bf16x8*)&att[(row0+row)*D_MODEL + col0 + c8] = *(const bf16x8*)&att_s[row*72 + c8];
    }
}

// ---------------------------------------------------------------------------
// Launch. Workspace (>= 224 MiB), aliasing:
//   [0,32)    rxb bf16   -> U f32 (after rkv GEMM)
//   [32,64)   kxb bf16   -> stT bf16
//   [64,96)   vxb bf16   -> att bf16
//   [96,128)  WT[4] bf16 (Wr,Wk,Wv,Wo transposed; Wo alive to end)
//   [128,160) rb, [160,192) kb, [192,224) vb
// ---------------------------------------------------------------------------
extern "C" void kernel_launch(void* const* d_in, const int* in_sizes, int n_in,
                              void* d_out, int out_size, void* d_ws, size_t ws_size,
                              hipStream_t stream) {
    const float* x   = (const float*)d_in[0];
    const float* tmr = (const float*)d_in[1];
    const float* tmk = (const float*)d_in[2];
    const float* tmv = (const float*)d_in[3];
    const float* Wk  = (const float*)d_in[4];
    const float* Wv  = (const float*)d_in[5];
    const float* Wr  = (const float*)d_in[6];
    const float* Wo  = (const float*)d_in[7];
    const float* td  = (const float*)d_in[8];
    const float* tf  = (const float*)d_in[9];
    const float* g1  = (const float*)d_in[10];
    const float* b1  = (const float*)d_in[11];
    const float* gx  = (const float*)d_in[12];
    const float* bx  = (const float*)d_in[13];

    float* out0 = (float*)d_out;
    float* out1 = out0 + (size_t)NTOK*D_MODEL;
    float* out2 = out1 + (size_t)BZ*D_MODEL;

    const size_t MB = 1ull<<20;
    char* ws = (char*)d_ws;
    bf16_t* rxb = (bf16_t*)(ws);
    bf16_t* kxb = (bf16_t*)(ws + 32*MB);
    bf16_t* vxb = (bf16_t*)(ws + 64*MB);
    bf16_t* WTb = (bf16_t*)(ws + 96*MB);          // 4 x 8MB: Wr,Wk,Wv,Wo
    bf16_t* WoT = (bf16_t*)(ws + 120*MB);
    bf16_t* rb  = (bf16_t*)(ws + 128*MB);
    float*  U   = (float*)(ws);                   // after rxb dead
    bf16_t* stT = (bf16_t*)(ws + 32*MB);          // after kxb dead
    bf16_t* att = (bf16_t*)(ws + 64*MB);          // after vxb dead
    bf16_t* kb  = (bf16_t*)(ws + 160*MB);
    bf16_t* vb  = (bf16_t*)(ws + 192*MB);

    k_ln_mix<<<NTOK, 256, 0, stream>>>(x, tmr, tmk, tmv, g1, b1, rxb, kxb, vxb, out1);

    dim3 gT(32, 32, 4);
    k_wt4<<<gT, 256, 0, stream>>>(Wr, Wk, Wv, Wo, WTb);

    dim3 gG3(D_MODEL/256, NTOK/256, 3);   // (8, 32, 3)
    k_gemm_rkv<<<gG3, 512, 0, stream>>>(rxb, WTb, rb);

    const int nblk = BZ*NC*N_HEADS;   // 2048
    k_chunk_U <<<nblk, 256, 0, stream>>>(kb, vb, td, U);
    k_scan    <<<256, 256, 0, stream>>>(U, td, stT, out2);
    k_att_fused<<<nblk, 256, 0, stream>>>(rb, kb, vb, stT, td, tf, gx, bx, att);

    dim3 gG(D_MODEL/256, NTOK/256);       // (8, 32)
    k_gemm_out<<<gG, 512, 0, stream>>>(att, WoT, out0, x);
}